// Round 18
// baseline (169.260 us; speedup 1.0000x reference)
//
#include <hip/hip_runtime.h>
#include <hip/hip_bf16.h>

typedef unsigned short u16;
typedef unsigned int u32;
typedef __attribute__((ext_vector_type(8))) __bf16 bf16x8;
typedef __attribute__((ext_vector_type(4))) float f32x4;

#define HID 2048
#define NH 16
#define HD 128
#define LAT 256
#define BATCH 4
#define SEQ 1024

__device__ __forceinline__ u16 f2bf(float f) {
  union { float f; u32 u; } v; v.f = f;
  u32 r = v.u + 0x7fffu + ((v.u >> 16) & 1u);
  return (u16)(r >> 16);
}

typedef const __attribute__((address_space(1))) u32 as1_u32;
typedef __attribute__((address_space(3))) u32 as3_u32;

__device__ __forceinline__ void load_lds16(const void* g, void* l) {
  __builtin_amdgcn_global_load_lds((as1_u32*)g, (as3_u32*)l, 16, 0, 0);
}

// ---------------- merged prep kernel (r16-proven) ----------------
__device__ __forceinline__ void prep_transpose(const float* __restrict__ in, u16* __restrict__ o,
                                               int R, int C, int bxi, int byi, int tid) {
  __shared__ float t[32][33];
  int bx = bxi * 32, by = byi * 32;
  int tx = tid & 31, ty = tid >> 5;
  #pragma unroll
  for (int i = ty; i < 32; i += 8) t[i][tx] = in[(size_t)(by + i) * C + bx + tx];
  __syncthreads();
  #pragma unroll
  for (int i = ty; i < 32; i += 8) o[(size_t)(bx + i) * R + by + tx] = f2bf(t[tx][i]);
}

__global__ void __launch_bounds__(256) k_prep(const float* __restrict__ x, u16* __restrict__ xb,
    const float* __restrict__ wqd, const float* __restrict__ wkvd,
    const float* __restrict__ wqu, const float* __restrict__ wku, const float* __restrict__ wvu,
    const float* __restrict__ wo,
    u16* __restrict__ wqdT, u16* __restrict__ wkvdT,
    u16* __restrict__ wquT, u16* __restrict__ wkuT, u16* __restrict__ wvuT,
    u16* __restrict__ woT, float* __restrict__ cosT, float* __restrict__ sinT) {
  const int bb = blockIdx.x, tid = threadIdx.x;
  if (bb < 8192) {
    int i = bb * 256 + tid;
    float4 v = ((const float4*)x)[i];
    union { u16 s[4]; uint2 u; } w;
    w.s[0] = f2bf(v.x); w.s[1] = f2bf(v.y); w.s[2] = f2bf(v.z); w.s[3] = f2bf(v.w);
    ((uint2*)xb)[i] = w.u;
  } else if (bb < 9216) {
    int i = bb - 8192;
    int z = i >> 9, r = i & 511;
    prep_transpose(z ? wkvd : wqd, z ? wkvdT : wqdT, 2048, 256, r & 7, r >> 3, tid);
  } else if (bb < 10752) {
    int i = bb - 9216;
    int z = i >> 9, r = i & 511;
    const float* in = (z == 0) ? wqu : (z == 1 ? wku : wvu);
    u16* o = (z == 0) ? wquT : (z == 1 ? wkuT : wvuT);
    prep_transpose(in, o, 256, 2048, r & 63, r >> 6, tid);
  } else if (bb < 14848) {
    int i = bb - 10752;
    prep_transpose(wo, woT, 2048, 2048, i & 63, i >> 6, tid);
  } else {
    int idx = (bb - 14848) * 256 + tid;
    int s = idx >> 6, d = idx & 63;
    float inv = powf(100000.0f, -(float)d / 64.0f);
    float a = (float)s * inv;
    cosT[idx] = cosf(a);
    sinT[idx] = sinf(a);
  }
}

// ---------------- stage kernels ----------------
// k_down v2 (r9-proven): 128x64 tile, BK=128, 8 waves, double-buffered counted-vmcnt.
__global__ void __launch_bounds__(512, 2) k_down(const u16* __restrict__ xb, const u16* __restrict__ wqdT,
    const u16* __restrict__ wkvdT, u16* __restrict__ ql, u16* __restrict__ kvl) {
  __shared__ __align__(16) u16 As[2][128 * 128];
  __shared__ __align__(16) u16 Bs[2][64 * 128];
  const u16* Bt = blockIdx.z ? wkvdT : wqdT;
  u16* out = blockIdx.z ? kvl : ql;
  const int rb = blockIdx.x * 128, cb = blockIdx.y * 64;
  const int tid = threadIdx.x, lane = tid & 63, wave = tid >> 6;
  const int wm = wave & 3, wn = wave >> 2;
  const int fr = lane & 15, fq = lane >> 4;
  const char* Ab = (const char*)xb;
  const char* Bb = (const char*)Bt;
  f32x4 acc[2][2] = {};

  auto stage = [&](int buf, int s) {
    #pragma unroll
    for (int cc = 0; cc < 4; ++cc) {
      int c = wave * 4 + cc;
      int L = c * 1024 + lane * 16;
      int Ls = L ^ (((L >> 8) & 7) << 4);
      int r = Ls >> 8, colb = Ls & 255;
      load_lds16(Ab + (size_t)(rb + r) * 4096 + s * 256 + colb, (char*)As[buf] + c * 1024);
    }
    #pragma unroll
    for (int cc = 0; cc < 2; ++cc) {
      int c = wave * 2 + cc;
      int L = c * 1024 + lane * 16;
      int Ls = L ^ (((L >> 8) & 7) << 4);
      int r = Ls >> 8, colb = Ls & 255;
      load_lds16(Bb + (size_t)(cb + r) * 4096 + s * 256 + colb, (char*)Bs[buf] + c * 1024);
    }
  };

  stage(0, 0);
  int buf = 0;
  for (int s = 0; s < 16; ++s) {
    if (s + 1 < 16) {
      stage(buf ^ 1, s + 1);
      asm volatile("s_waitcnt vmcnt(6)" ::: "memory");
    } else {
      asm volatile("s_waitcnt vmcnt(0)" ::: "memory");
    }
    asm volatile("s_barrier" ::: "memory");

    #pragma unroll
    for (int kk = 0; kk < 4; ++kk) {
      bf16x8 af[2], bfr[2];
      #pragma unroll
      for (int m = 0; m < 2; ++m) {
        int r = wm * 32 + m * 16 + fr;
        af[m] = *(const bf16x8*)((const char*)As[buf] + ((r * 256 + kk * 64 + fq * 16) ^ ((r & 7) << 4)));
      }
      #pragma unroll
      for (int n = 0; n < 2; ++n) {
        int r = wn * 32 + n * 16 + fr;
        bfr[n] = *(const bf16x8*)((const char*)Bs[buf] + ((r * 256 + kk * 64 + fq * 16) ^ ((r & 7) << 4)));
      }
      #pragma unroll
      for (int m = 0; m < 2; ++m)
        #pragma unroll
        for (int n = 0; n < 2; ++n)
          acc[m][n] = __builtin_amdgcn_mfma_f32_16x16x32_bf16(af[m], bfr[n], acc[m][n], 0, 0, 0);
    }

    asm volatile("s_barrier" ::: "memory");
    buf ^= 1;
  }

  #pragma unroll
  for (int m = 0; m < 2; ++m)
    #pragma unroll
    for (int n = 0; n < 2; ++n)
      #pragma unroll
      for (int i = 0; i < 4; ++i)
        out[(size_t)(rb + wm * 32 + m * 16 + fq * 4 + i) * LAT + cb + wn * 32 + n * 16 + fr] =
            f2bf(acc[m][n][i]);
}

// k_up v2 (r17-proven): 128x128 tile (one head), BK=64, dbuf counted-vmcnt(8), 4 waves.
__global__ void __launch_bounds__(256, 2) k_up(const u16* __restrict__ ql, const u16* __restrict__ kvl,
    const u16* __restrict__ wquT, const u16* __restrict__ wkuT, const u16* __restrict__ wvuT,
    u16* __restrict__ q, u16* __restrict__ k, u16* __restrict__ vt,
    const float* __restrict__ cosT, const float* __restrict__ sinT) {
  __shared__ __align__(16) u16 As[2][128 * 64];
  __shared__ __align__(16) u16 Bs[2][128 * 64];
  const int mode = blockIdx.z;
  const u16* A = (mode == 0) ? ql : kvl;
  const u16* Bt = (mode == 0) ? wquT : (mode == 1 ? wkuT : wvuT);
  const int rb = blockIdx.x * 128;
  const int h = blockIdx.y;
  const int tid = threadIdx.x, lane = tid & 63, wave = tid >> 6;
  const int fr = lane & 15, fq = lane >> 4;
  const char* Ab = (const char*)A;
  const char* Bb = (const char*)Bt;
  f32x4 acc[2][8] = {};

  auto stage = [&](int buf, int s) {
    #pragma unroll
    for (int cc = 0; cc < 4; ++cc) {
      int c = wave * 4 + cc;
      int L = c * 1024 + lane * 16;
      int Ls = L ^ (((L >> 7) & 7) << 4);
      int r = Ls >> 7, colb = Ls & 127;
      load_lds16(Ab + (size_t)(rb + r) * 512 + s * 128 + colb, (char*)As[buf] + c * 1024);
      load_lds16(Bb + (size_t)(h * HD + r) * 512 + s * 128 + colb, (char*)Bs[buf] + c * 1024);
    }
  };

  stage(0, 0);
  int buf = 0;
  for (int s = 0; s < 4; ++s) {
    if (s + 1 < 4) {
      stage(buf ^ 1, s + 1);
      asm volatile("s_waitcnt vmcnt(8)" ::: "memory");
    } else {
      asm volatile("s_waitcnt vmcnt(0)" ::: "memory");
    }
    asm volatile("s_barrier" ::: "memory");

    #pragma unroll
    for (int kk = 0; kk < 2; ++kk) {
      bf16x8 af[2], bfr[8];
      #pragma unroll
      for (int m = 0; m < 2; ++m) {
        int r = wave * 32 + m * 16 + fr;
        af[m] = *(const bf16x8*)((const char*)As[buf] + ((r * 128 + kk * 64 + fq * 16) ^ ((r & 7) << 4)));
      }
      #pragma unroll
      for (int n = 0; n < 8; ++n) {
        int r = n * 16 + fr;
        bfr[n] = *(const bf16x8*)((const char*)Bs[buf] + ((r * 128 + kk * 64 + fq * 16) ^ ((r & 7) << 4)));
      }
      #pragma unroll
      for (int m = 0; m < 2; ++m)
        #pragma unroll
        for (int n = 0; n < 8; ++n)
          acc[m][n] = __builtin_amdgcn_mfma_f32_16x16x32_bf16(af[m], bfr[n], acc[m][n], 0, 0, 0);
    }

    asm volatile("s_barrier" ::: "memory");
    buf ^= 1;
  }

  if (mode == 2) {
    #pragma unroll
    for (int m = 0; m < 2; ++m)
      #pragma unroll
      for (int n = 0; n < 8; ++n)
        #pragma unroll
        for (int i = 0; i < 4; ++i) {
          int row = rb + wave * 32 + m * 16 + fq * 4 + i;
          int b = row >> 10, s = row & 1023;
          int sp = (s & ~63) | (((s >> 4) & 1) << 5) | (((s >> 3) & 1) << 4) |
                   (((s >> 2) & 1) << 3) | (((s >> 5) & 1) << 2) | (s & 3);
          vt[(size_t)((b * NH + h) * HD + n * 16 + fr) * SEQ + sp] = f2bf(acc[m][n][i]);
        }
  } else {
    u16* dst = (mode == 0) ? q : k;
    const float scale = (mode == 0) ? 0.08838834764831845f * 1.4426950408889634f : 1.0f;
    #pragma unroll
    for (int m = 0; m < 2; ++m)
      #pragma unroll
      for (int i = 0; i < 4; ++i) {
        int row = rb + wave * 32 + m * 16 + fq * 4 + i;
        int b = row >> 10, s = row & 1023;
        size_t base = (size_t)((b * NH + h) * SEQ + s) * HD;
        #pragma unroll
        for (int j = 0; j < 4; ++j) {
          int dlo = j * 16 + fr;
          float c = cosT[s * 64 + dlo], sn = sinT[s * 64 + dlo];
          float x1 = acc[m][j][i], x2 = acc[m][j + 4][i];
          dst[base + dlo] = f2bf((x1 * c - x2 * sn) * scale);
          dst[base + dlo + 64] = f2bf((x2 * c + x1 * sn) * scale);
        }
      }
  }
}

// flash attention v13: r13 shell + KVBLK=128 (128KB LDS, 1 block/CU -> fits in 160KB).
// Tile processed as TWO sequential 64-k halves (keeps r13's register profile: sc[4],
// pa[2] live per half -> no spill; r14 lesson). Barrier pairs per block HALVED (13->7).
// 16 waves, 4/SIMD; waves 0-7 q-tile jh=7-jp, 8-15 jl=jp sharing staged K/V.
// counted vmcnt(4); in-register P (swapped QK^T + kappa V per 64-group); XCD-local bh;
// shift-free exp2 softmax; ones-trick row-sum; T5 setprio.
__global__ void __launch_bounds__(1024, 1) k_attn(const u16* __restrict__ Q, const u16* __restrict__ Kc,
    const u16* __restrict__ Vt, u16* __restrict__ O) {
  __shared__ __align__(16) u16 Ks[2][128 * 128];  // [k-row][d], row=256B, swz bits4-6^(r&7)
  __shared__ __align__(16) u16 Vs[2][128 * 128];  // [d][2x kappa(k) 64-groups], row=256B, swz
  const int f = blockIdx.x;                       // 256 blocks
  const int bh = (f & 7) * 8 + ((f >> 3) & 7);    // 8 bh per XCD (L2 locality)
  const int jp = f >> 6;                          // 0..3
  const int jh = 7 - jp, jl = jp;
  const int h = bh & (NH - 1), b = bh >> 4;
  const int tid = threadIdx.x, lane = tid & 63, wave = tid >> 6;  // wave 0..15
  const int fr = lane & 15, fq = lane >> 4;
  const int qw = ((wave < 8) ? jh : jl) * 128 + (wave & 7) * 16;  // wave's 16 q-rows
  const size_t qkb = (size_t)bh * SEQ * HD;
  const char* Kbase = (const char*)Kc + qkb * 2;
  const char* Vbase = (const char*)Vt + (size_t)bh * HD * SEQ * 2;
  const int nkt = jh + 1;                         // 128-k tiles (heavy range)

  // stage 64KB with 16 waves: 4 chunks of 1KB per wave (2 K + 2 V)
  auto stage = [&](int buf, int kt) {
    #pragma unroll
    for (int cc = 0; cc < 2; ++cc) {
      int c = wave * 2 + cc;
      int L = c * 1024 + lane * 16;
      int Ls = L ^ (((L >> 8) & 7) << 4);
      load_lds16(Kbase + (size_t)kt * 32768 + Ls, (char*)Ks[buf] + c * 1024);
      int rv = Ls >> 8, colb = Ls & 255;
      load_lds16(Vbase + (size_t)rv * (SEQ * 2) + (size_t)kt * 256 + colb, (char*)Vs[buf] + c * 1024);
    }
  };

  bf16x8 ones;
  #pragma unroll
  for (int z = 0; z < 8; ++z) ones[z] = (__bf16)1.0f;

  bf16x8 qf[4];
  #pragma unroll
  for (int c = 0; c < 4; ++c)
    qf[c] = *(const bf16x8*)&Q[qkb + (size_t)(qw + fr) * HD + c * 32 + fq * 8];

  f32x4 ao[8] = {};
  f32x4 lacc = {};

  stage(0, 0);

  int cur = 0;
  for (int t = 0; t < nkt; ++t) {
    if (t + 1 < nkt) {
      stage(cur ^ 1, t + 1);                               // issue next (4 loads)
      asm volatile("s_waitcnt vmcnt(4)" ::: "memory");     // my stage(t) landed
    } else {
      asm volatile("s_waitcnt vmcnt(0)" ::: "memory");
    }
    asm volatile("s_barrier" ::: "memory");                // all waves' stage(t) landed

    #pragma unroll
    for (int kh = 0; kh < 2; ++kh) {                       // two 64-k halves, sequential
      const int k0 = t * 128 + kh * 64;
      if (k0 <= qw + 15) {                                 // wave-uniform skip
        // ---- QK^T (swapped): sc[n] = S^T; thread: k=kh*64+n*16+fq*4+i, q=fr ----
        f32x4 sc[4] = {};
        __builtin_amdgcn_s_setprio(1);
        #pragma unroll
        for (int c = 0; c < 4; ++c)
          #pragma unroll
          for (int n = 0; n < 4; ++n) {
            int rr = kh * 64 + n * 16 + fr;
            int off = (rr * 256 + c * 64 + fq * 16) ^ ((rr & 7) << 4);
            bf16x8 kf = *(const bf16x8*)((const char*)Ks[cur] + off);
            sc[n] = __builtin_amdgcn_mfma_f32_16x16x32_bf16(kf, qf[c], sc[n], 0, 0, 0);
          }
        __builtin_amdgcn_s_setprio(0);

        // ---- in-register softmax ----
        const bool needmask = (k0 + 63 > qw);
        const int qrow = qw + fr;
        float p[4][4];
        #pragma unroll
        for (int n = 0; n < 4; ++n)
          #pragma unroll
          for (int i = 0; i < 4; ++i) {
            float sv = sc[n][i];
            if (needmask) {
              int kg = k0 + n * 16 + fq * 4 + i;
              sv = (kg <= qrow) ? sv : -1e30f;
            }
            p[n][i] = exp2f(sv);
          }
        bf16x8 pa[2];
        #pragma unroll
        for (int kf = 0; kf < 2; ++kf) {
          union { bf16x8 v; u32 w[4]; } pu;
          asm("v_cvt_pk_bf16_f32 %0, %1, %2" : "=v"(pu.w[0]) : "v"(p[kf][0]), "v"(p[kf][1]));
          asm("v_cvt_pk_bf16_f32 %0, %1, %2" : "=v"(pu.w[1]) : "v"(p[kf][2]), "v"(p[kf][3]));
          asm("v_cvt_pk_bf16_f32 %0, %1, %2" : "=v"(pu.w[2]) : "v"(p[2 + kf][0]), "v"(p[2 + kf][1]));
          asm("v_cvt_pk_bf16_f32 %0, %1, %2" : "=v"(pu.w[3]) : "v"(p[2 + kf][2]), "v"(p[2 + kf][3]));
          pa[kf] = pu.v;
        }

        // ---- l += P @ ones; PV: O(16x128) += P(16x64) V(64x128) ----
        __builtin_amdgcn_s_setprio(1);
        lacc = __builtin_amdgcn_mfma_f32_16x16x32_bf16(pa[0], ones, lacc, 0, 0, 0);
        lacc = __builtin_amdgcn_mfma_f32_16x16x32_bf16(pa[1], ones, lacc, 0, 0, 0);
        #pragma unroll
        for (int jj = 0; jj < 8; ++jj)
          #pragma unroll
          for (int kf = 0; kf < 2; ++kf) {
            int rv = jj * 16 + fr;
            int off = (rv * 256 + kh * 128 + kf * 64 + fq * 16) ^ ((rv & 7) << 4);
            bf16x8 vf = *(const bf16x8*)((const char*)Vs[cur] + off);
            ao[jj] = __builtin_amdgcn_mfma_f32_16x16x32_bf16(pa[kf], vf, ao[jj], 0, 0, 0);
          }
        __builtin_amdgcn_s_setprio(0);
      }
    }
    asm volatile("s_barrier" ::: "memory");                // all waves done reading buf[cur]
    cur ^= 1;
  }

  // epilogue: ao rows q = qw + fq*4 + i, cols d = jj*16 + fr
  #pragma unroll
  for (int i = 0; i < 4; ++i) {
    float inv = 1.f / lacc[i];
    int s = qw + fq * 4 + i;
    size_t base = (size_t)(b * SEQ + s) * HID + h * HD;
    #pragma unroll
    for (int jj = 0; jj < 8; ++jj)
      O[base + jj * 16 + fr] = f2bf(ao[jj][i] * inv);
  }
}

// k_out v2 (r7-proven, 43.6us): 128x128 tile, BK=128, single-buffered 64KB ->
// 2 blocks/CU (grid 512 = 2/CU; sibling hides the drain, m114), both-sides XOR swizzle.
__global__ void __launch_bounds__(256) k_out(const u16* __restrict__ at, const u16* __restrict__ woT,
    float* __restrict__ out) {
  __shared__ __align__(16) u16 As[128 * 128];   // 32KB, [row][128k], swz
  __shared__ __align__(16) u16 Bs[128 * 128];   // 32KB
  const int rb = blockIdx.x * 128, cb = blockIdx.y * 128;
  const int tid = threadIdx.x, lane = tid & 63, wave = tid >> 6;
  const int wm = wave & 1, wn = wave >> 1;
  const int fr = lane & 15, fq = lane >> 4;
  const char* Ab = (const char*)at;   // row stride 4096B
  const char* Bb = (const char*)woT;

  f32x4 acc[4][4] = {};

  for (int kt = 0; kt < HID; kt += 128) {
    __syncthreads();
    #pragma unroll
    for (int cc = 0; cc < 8; ++cc) {
      int c = wave * 8 + cc;
      int L = c * 1024 + lane * 16;
      int Ls = L ^ (((L >> 8) & 7) << 4);
      int r = Ls >> 8, colb = Ls & 255;
      load_lds16(Ab + (size_t)(rb + r) * (HID * 2) + kt * 2 + colb, (char*)As + c * 1024);
      load_lds16(Bb + (size_t)(cb + r) * (HID * 2) + kt * 2 + colb, (char*)Bs + c * 1024);
    }
    asm volatile("s_waitcnt vmcnt(0)" ::: "memory");
    __syncthreads();

    #pragma unroll
    for (int kk = 0; kk < 4; ++kk) {
      bf16x8 af[4], bfr[4];
      #pragma unroll
      for (int m = 0; m < 4; ++m) {
        int r = wm * 64 + m * 16 + fr;
        af[m] = *(const bf16x8*)((const char*)As + ((r * 256 + kk * 64 + fq * 16) ^ ((r & 7) << 4)));
      }
      #pragma unroll
      for (int n = 0; n < 4; ++n) {
        int r = wn * 64 + n * 16 + fr;
        bfr[n] = *(const bf16x8*)((const char*)Bs + ((r * 256 + kk * 64 + fq * 16) ^ ((r & 7) << 4)));
      }
      #pragma unroll
      for (int m = 0; m < 4; ++m)
        #pragma unroll
        for (int n = 0; n < 4; ++n)
          acc[m][n] = __builtin_amdgcn_mfma_f32_16x16x32_bf16(af[m], bfr[n], acc[m][n], 0, 0, 0);
    }
  }

  #pragma unroll
  for (int m = 0; m < 4; ++m)
    #pragma unroll
    for (int n = 0; n < 4; ++n)
      #pragma unroll
      for (int i = 0; i < 4; ++i)
        out[(size_t)(rb + wm * 64 + m * 16 + fq * 4 + i) * HID + cb + wn * 64 + n * 16 + fr] =
            acc[m][n][i];
}

extern "C" void kernel_launch(void* const* d_in, const int* in_sizes, int n_in,
                              void* d_out, int out_size, void* d_ws, size_t ws_size,
                              hipStream_t stream) {
  const float* x    = (const float*)d_in[0];
  const float* wqd  = (const float*)d_in[1];
  const float* wkvd = (const float*)d_in[2];
  const float* wqu  = (const float*)d_in[3];
  const float* wku  = (const float*)d_in[4];
  const float* wvu  = (const float*)d_in[5];
  const float* wo   = (const float*)d_in[6];
  float* out = (float*)d_out;

  char* p = (char*)d_ws;
  u16* xb    = (u16*)(p + 0);
  u16* at    = xb;
  u16* wqdT  = (u16*)(p + 16777216);
  u16* wkvdT = (u16*)(p + 17825792);
  u16* wquT  = (u16*)(p + 18874368);
  u16* wkuT  = (u16*)(p + 19922944);
  u16* wvuT  = (u16*)(p + 20971520);
  u16* woT   = (u16*)(p + 22020096);
  u16* ql    = (u16*)(p + 30408704);
  u16* kvl   = (u16*)(p + 32505856);
  u16* q     = (u16*)(p + 34603008);
  u16* kk    = (u16*)(p + 51380224);
  u16* vt    = (u16*)(p + 68157440);
  float* cosT = (float*)(p + 84934656);
  float* sinT = (float*)(p + 85196800);

  k_prep<<<15104, 256, 0, stream>>>(x, xb, wqd, wkvd, wqu, wku, wvu, wo,
                                    wqdT, wkvdT, wquT, wkuT, wvuT, woT, cosT, sinT);

  k_down<<<dim3(32, 4, 2), 512, 0, stream>>>(xb, wqdT, wkvdT, ql, kvl);
  k_up<<<dim3(32, 16, 3), 256, 0, stream>>>(ql, kvl, wquT, wkuT, wvuT, q, kk, vt, cosT, sinT);
  k_attn<<<256, 1024, 0, stream>>>(q, kk, vt, at);
  k_out<<<dim3(32, 16), 256, 0, stream>>>(at, woT, out);
}

// Round 19
// 139.097 us; speedup vs baseline: 1.2169x; 1.2169x over previous
//
#include <hip/hip_runtime.h>
#include <hip/hip_bf16.h>

typedef unsigned short u16;
typedef unsigned int u32;
typedef __attribute__((ext_vector_type(8))) __bf16 bf16x8;
typedef __attribute__((ext_vector_type(4))) float f32x4;

#define HID 2048
#define NH 16
#define HD 128
#define LAT 256
#define BATCH 4
#define SEQ 1024

__device__ __forceinline__ u16 f2bf(float f) {
  union { float f; u32 u; } v; v.f = f;
  u32 r = v.u + 0x7fffu + ((v.u >> 16) & 1u);
  return (u16)(r >> 16);
}

typedef const __attribute__((address_space(1))) u32 as1_u32;
typedef __attribute__((address_space(3))) u32 as3_u32;

__device__ __forceinline__ void load_lds16(const void* g, void* l) {
  __builtin_amdgcn_global_load_lds((as1_u32*)g, (as3_u32*)l, 16, 0, 0);
}

// ---------------- merged prep kernel (r16-proven) ----------------
__device__ __forceinline__ void prep_transpose(const float* __restrict__ in, u16* __restrict__ o,
                                               int R, int C, int bxi, int byi, int tid) {
  __shared__ float t[32][33];
  int bx = bxi * 32, by = byi * 32;
  int tx = tid & 31, ty = tid >> 5;
  #pragma unroll
  for (int i = ty; i < 32; i += 8) t[i][tx] = in[(size_t)(by + i) * C + bx + tx];
  __syncthreads();
  #pragma unroll
  for (int i = ty; i < 32; i += 8) o[(size_t)(bx + i) * R + by + tx] = f2bf(t[tx][i]);
}

__global__ void __launch_bounds__(256) k_prep(const float* __restrict__ x, u16* __restrict__ xb,
    const float* __restrict__ wqd, const float* __restrict__ wkvd,
    const float* __restrict__ wqu, const float* __restrict__ wku, const float* __restrict__ wvu,
    const float* __restrict__ wo,
    u16* __restrict__ wqdT, u16* __restrict__ wkvdT,
    u16* __restrict__ wquT, u16* __restrict__ wkuT, u16* __restrict__ wvuT,
    u16* __restrict__ woT, float* __restrict__ cosT, float* __restrict__ sinT) {
  const int bb = blockIdx.x, tid = threadIdx.x;
  if (bb < 8192) {
    int i = bb * 256 + tid;
    float4 v = ((const float4*)x)[i];
    union { u16 s[4]; uint2 u; } w;
    w.s[0] = f2bf(v.x); w.s[1] = f2bf(v.y); w.s[2] = f2bf(v.z); w.s[3] = f2bf(v.w);
    ((uint2*)xb)[i] = w.u;
  } else if (bb < 9216) {
    int i = bb - 8192;
    int z = i >> 9, r = i & 511;
    prep_transpose(z ? wkvd : wqd, z ? wkvdT : wqdT, 2048, 256, r & 7, r >> 3, tid);
  } else if (bb < 10752) {
    int i = bb - 9216;
    int z = i >> 9, r = i & 511;
    const float* in = (z == 0) ? wqu : (z == 1 ? wku : wvu);
    u16* o = (z == 0) ? wquT : (z == 1 ? wkuT : wvuT);
    prep_transpose(in, o, 256, 2048, r & 63, r >> 6, tid);
  } else if (bb < 14848) {
    int i = bb - 10752;
    prep_transpose(wo, woT, 2048, 2048, i & 63, i >> 6, tid);
  } else {
    int idx = (bb - 14848) * 256 + tid;
    int s = idx >> 6, d = idx & 63;
    float inv = powf(100000.0f, -(float)d / 64.0f);
    float a = (float)s * inv;
    cosT[idx] = cosf(a);
    sinT[idx] = sinf(a);
  }
}

// ---------------- stage kernels ----------------
// k_down v2 (r9-proven): 128x64 tile, BK=128, 8 waves, double-buffered counted-vmcnt.
__global__ void __launch_bounds__(512, 2) k_down(const u16* __restrict__ xb, const u16* __restrict__ wqdT,
    const u16* __restrict__ wkvdT, u16* __restrict__ ql, u16* __restrict__ kvl) {
  __shared__ __align__(16) u16 As[2][128 * 128];
  __shared__ __align__(16) u16 Bs[2][64 * 128];
  const u16* Bt = blockIdx.z ? wkvdT : wqdT;
  u16* out = blockIdx.z ? kvl : ql;
  const int rb = blockIdx.x * 128, cb = blockIdx.y * 64;
  const int tid = threadIdx.x, lane = tid & 63, wave = tid >> 6;
  const int wm = wave & 3, wn = wave >> 2;
  const int fr = lane & 15, fq = lane >> 4;
  const char* Ab = (const char*)xb;
  const char* Bb = (const char*)Bt;
  f32x4 acc[2][2] = {};

  auto stage = [&](int buf, int s) {
    #pragma unroll
    for (int cc = 0; cc < 4; ++cc) {
      int c = wave * 4 + cc;
      int L = c * 1024 + lane * 16;
      int Ls = L ^ (((L >> 8) & 7) << 4);
      int r = Ls >> 8, colb = Ls & 255;
      load_lds16(Ab + (size_t)(rb + r) * 4096 + s * 256 + colb, (char*)As[buf] + c * 1024);
    }
    #pragma unroll
    for (int cc = 0; cc < 2; ++cc) {
      int c = wave * 2 + cc;
      int L = c * 1024 + lane * 16;
      int Ls = L ^ (((L >> 8) & 7) << 4);
      int r = Ls >> 8, colb = Ls & 255;
      load_lds16(Bb + (size_t)(cb + r) * 4096 + s * 256 + colb, (char*)Bs[buf] + c * 1024);
    }
  };

  stage(0, 0);
  int buf = 0;
  for (int s = 0; s < 16; ++s) {
    if (s + 1 < 16) {
      stage(buf ^ 1, s + 1);
      asm volatile("s_waitcnt vmcnt(6)" ::: "memory");
    } else {
      asm volatile("s_waitcnt vmcnt(0)" ::: "memory");
    }
    asm volatile("s_barrier" ::: "memory");

    #pragma unroll
    for (int kk = 0; kk < 4; ++kk) {
      bf16x8 af[2], bfr[2];
      #pragma unroll
      for (int m = 0; m < 2; ++m) {
        int r = wm * 32 + m * 16 + fr;
        af[m] = *(const bf16x8*)((const char*)As[buf] + ((r * 256 + kk * 64 + fq * 16) ^ ((r & 7) << 4)));
      }
      #pragma unroll
      for (int n = 0; n < 2; ++n) {
        int r = wn * 32 + n * 16 + fr;
        bfr[n] = *(const bf16x8*)((const char*)Bs[buf] + ((r * 256 + kk * 64 + fq * 16) ^ ((r & 7) << 4)));
      }
      #pragma unroll
      for (int m = 0; m < 2; ++m)
        #pragma unroll
        for (int n = 0; n < 2; ++n)
          acc[m][n] = __builtin_amdgcn_mfma_f32_16x16x32_bf16(af[m], bfr[n], acc[m][n], 0, 0, 0);
    }

    asm volatile("s_barrier" ::: "memory");
    buf ^= 1;
  }

  #pragma unroll
  for (int m = 0; m < 2; ++m)
    #pragma unroll
    for (int n = 0; n < 2; ++n)
      #pragma unroll
      for (int i = 0; i < 4; ++i)
        out[(size_t)(rb + wm * 32 + m * 16 + fq * 4 + i) * LAT + cb + wn * 32 + n * 16 + fr] =
            f2bf(acc[m][n][i]);
}

// k_up v2 (r17-proven): 128x128 tile (one head), BK=64, dbuf counted-vmcnt(8), 4 waves.
__global__ void __launch_bounds__(256, 2) k_up(const u16* __restrict__ ql, const u16* __restrict__ kvl,
    const u16* __restrict__ wquT, const u16* __restrict__ wkuT, const u16* __restrict__ wvuT,
    u16* __restrict__ q, u16* __restrict__ k, u16* __restrict__ vt,
    const float* __restrict__ cosT, const float* __restrict__ sinT) {
  __shared__ __align__(16) u16 As[2][128 * 64];
  __shared__ __align__(16) u16 Bs[2][128 * 64];
  const int mode = blockIdx.z;
  const u16* A = (mode == 0) ? ql : kvl;
  const u16* Bt = (mode == 0) ? wquT : (mode == 1 ? wkuT : wvuT);
  const int rb = blockIdx.x * 128;
  const int h = blockIdx.y;
  const int tid = threadIdx.x, lane = tid & 63, wave = tid >> 6;
  const int fr = lane & 15, fq = lane >> 4;
  const char* Ab = (const char*)A;
  const char* Bb = (const char*)Bt;
  f32x4 acc[2][8] = {};

  auto stage = [&](int buf, int s) {
    #pragma unroll
    for (int cc = 0; cc < 4; ++cc) {
      int c = wave * 4 + cc;
      int L = c * 1024 + lane * 16;
      int Ls = L ^ (((L >> 7) & 7) << 4);
      int r = Ls >> 7, colb = Ls & 127;
      load_lds16(Ab + (size_t)(rb + r) * 512 + s * 128 + colb, (char*)As[buf] + c * 1024);
      load_lds16(Bb + (size_t)(h * HD + r) * 512 + s * 128 + colb, (char*)Bs[buf] + c * 1024);
    }
  };

  stage(0, 0);
  int buf = 0;
  for (int s = 0; s < 4; ++s) {
    if (s + 1 < 4) {
      stage(buf ^ 1, s + 1);
      asm volatile("s_waitcnt vmcnt(8)" ::: "memory");
    } else {
      asm volatile("s_waitcnt vmcnt(0)" ::: "memory");
    }
    asm volatile("s_barrier" ::: "memory");

    #pragma unroll
    for (int kk = 0; kk < 2; ++kk) {
      bf16x8 af[2], bfr[8];
      #pragma unroll
      for (int m = 0; m < 2; ++m) {
        int r = wave * 32 + m * 16 + fr;
        af[m] = *(const bf16x8*)((const char*)As[buf] + ((r * 128 + kk * 64 + fq * 16) ^ ((r & 7) << 4)));
      }
      #pragma unroll
      for (int n = 0; n < 8; ++n) {
        int r = n * 16 + fr;
        bfr[n] = *(const bf16x8*)((const char*)Bs[buf] + ((r * 128 + kk * 64 + fq * 16) ^ ((r & 7) << 4)));
      }
      #pragma unroll
      for (int m = 0; m < 2; ++m)
        #pragma unroll
        for (int n = 0; n < 8; ++n)
          acc[m][n] = __builtin_amdgcn_mfma_f32_16x16x32_bf16(af[m], bfr[n], acc[m][n], 0, 0, 0);
    }

    asm volatile("s_barrier" ::: "memory");
    buf ^= 1;
  }

  if (mode == 2) {
    #pragma unroll
    for (int m = 0; m < 2; ++m)
      #pragma unroll
      for (int n = 0; n < 8; ++n)
        #pragma unroll
        for (int i = 0; i < 4; ++i) {
          int row = rb + wave * 32 + m * 16 + fq * 4 + i;
          int b = row >> 10, s = row & 1023;
          int sp = (s & ~63) | (((s >> 4) & 1) << 5) | (((s >> 3) & 1) << 4) |
                   (((s >> 2) & 1) << 3) | (((s >> 5) & 1) << 2) | (s & 3);
          vt[(size_t)((b * NH + h) * HD + n * 16 + fr) * SEQ + sp] = f2bf(acc[m][n][i]);
        }
  } else {
    u16* dst = (mode == 0) ? q : k;
    const float scale = (mode == 0) ? 0.08838834764831845f * 1.4426950408889634f : 1.0f;
    #pragma unroll
    for (int m = 0; m < 2; ++m)
      #pragma unroll
      for (int i = 0; i < 4; ++i) {
        int row = rb + wave * 32 + m * 16 + fq * 4 + i;
        int b = row >> 10, s = row & 1023;
        size_t base = (size_t)((b * NH + h) * SEQ + s) * HD;
        #pragma unroll
        for (int j = 0; j < 4; ++j) {
          int dlo = j * 16 + fr;
          float c = cosT[s * 64 + dlo], sn = sinT[s * 64 + dlo];
          float x1 = acc[m][j][i], x2 = acc[m][j + 4][i];
          dst[base + dlo] = f2bf((x1 * c - x2 * sn) * scale);
          dst[base + dlo + 64] = f2bf((x2 * c + x1 * sn) * scale);
        }
      }
  }
}

// flash attention v11 (r13-proven, best): 256 blocks x 16 waves (1024 thr), 1 block/CU =
// 4 waves/SIMD. Waves 0-7 own q-tile jh=7-jp, waves 8-15 own jl=jp; both halves share
// staged K/V tiles. KVBLK=64 dbuf (64KB), counted vmcnt(2); in-register P (swapped
// QK^T + kappa V); XCD-local bh; shift-free exp2 softmax; ones-trick row-sum; setprio.
// NOTE: 16-wave shell caps VGPR at 128 — ONLY this exact body fits; any widening
// (32-row waves r14, KVBLK=128 r18) spills to scratch and doubles the runtime.
__global__ void __launch_bounds__(1024, 1) k_attn(const u16* __restrict__ Q, const u16* __restrict__ Kc,
    const u16* __restrict__ Vt, u16* __restrict__ O) {
  __shared__ __align__(16) u16 Ks[2][64 * 128];   // row=256B, swz bits4-6 ^ (row&7)
  __shared__ __align__(16) u16 Vs[2][128 * 64];   // [d][kappa(k)], row=128B, swz
  const int f = blockIdx.x;                       // 256 blocks
  const int bh = (f & 7) * 8 + ((f >> 3) & 7);    // 8 bh per XCD (L2 locality)
  const int jp = f >> 6;                          // 0..3
  const int jh = 7 - jp, jl = jp;
  const int h = bh & (NH - 1), b = bh >> 4;
  const int tid = threadIdx.x, lane = tid & 63, wave = tid >> 6;  // wave 0..15
  const int fr = lane & 15, fq = lane >> 4;
  const int qw = ((wave < 8) ? jh : jl) * 128 + (wave & 7) * 16;  // wave's 16 q-rows
  const size_t qkb = (size_t)bh * SEQ * HD;
  const char* Kbase = (const char*)Kc + qkb * 2;
  const char* Vbase = (const char*)Vt + (size_t)bh * HD * SEQ * 2;
  const int nkt = 2 * jh + 2;                     // heavy tile count (block-wide)

  auto stage = [&](int buf, int kt) {             // 2 loads per wave (1 K + 1 V)
    int c = wave;
    int L = c * 1024 + lane * 16;
    int Lk = L ^ (((L >> 8) & 7) << 4);
    load_lds16(Kbase + (size_t)kt * 16384 + Lk, (char*)Ks[buf] + c * 1024);
    int Lv = L ^ (((L >> 7) & 7) << 4);
    int rv = Lv >> 7, colb = Lv & 127;
    load_lds16(Vbase + (size_t)rv * (SEQ * 2) + (size_t)kt * 128 + colb, (char*)Vs[buf] + c * 1024);
  };

  bf16x8 ones;
  #pragma unroll
  for (int z = 0; z < 8; ++z) ones[z] = (__bf16)1.0f;

  bf16x8 qf[4];
  #pragma unroll
  for (int c = 0; c < 4; ++c)
    qf[c] = *(const bf16x8*)&Q[qkb + (size_t)(qw + fr) * HD + c * 32 + fq * 8];

  f32x4 ao[8] = {};
  f32x4 lacc = {};

  stage(0, 0);

  int cur = 0;
  for (int t = 0; t < nkt; ++t) {
    if (t + 1 < nkt) {
      stage(cur ^ 1, t + 1);
      asm volatile("s_waitcnt vmcnt(2)" ::: "memory");
    } else {
      asm volatile("s_waitcnt vmcnt(0)" ::: "memory");
    }
    asm volatile("s_barrier" ::: "memory");

    const int k0 = t * 64;
    if (k0 <= qw + 15) {
      // ---- QK^T (swapped): sc[n] = S^T tile; thread: k=n*16+fq*4+i, q=fr ----
      f32x4 sc[4] = {};
      __builtin_amdgcn_s_setprio(1);
      #pragma unroll
      for (int c = 0; c < 4; ++c)
        #pragma unroll
        for (int n = 0; n < 4; ++n) {
          int rr = n * 16 + fr;
          int off = (rr * 256 + c * 64 + fq * 16) ^ ((rr & 7) << 4);
          bf16x8 kf = *(const bf16x8*)((const char*)Ks[cur] + off);
          sc[n] = __builtin_amdgcn_mfma_f32_16x16x32_bf16(kf, qf[c], sc[n], 0, 0, 0);
        }
      __builtin_amdgcn_s_setprio(0);

      // ---- in-register softmax ----
      const bool needmask = (k0 + 63 > qw);
      const int qrow = qw + fr;
      float p[4][4];
      #pragma unroll
      for (int n = 0; n < 4; ++n)
        #pragma unroll
        for (int i = 0; i < 4; ++i) {
          float sv = sc[n][i];
          if (needmask) {
            int kg = k0 + n * 16 + fq * 4 + i;
            sv = (kg <= qrow) ? sv : -1e30f;
          }
          p[n][i] = exp2f(sv);
        }
      bf16x8 pa[2];
      #pragma unroll
      for (int kf = 0; kf < 2; ++kf) {
        union { bf16x8 v; u32 w[4]; } pu;
        asm("v_cvt_pk_bf16_f32 %0, %1, %2" : "=v"(pu.w[0]) : "v"(p[kf][0]), "v"(p[kf][1]));
        asm("v_cvt_pk_bf16_f32 %0, %1, %2" : "=v"(pu.w[1]) : "v"(p[kf][2]), "v"(p[kf][3]));
        asm("v_cvt_pk_bf16_f32 %0, %1, %2" : "=v"(pu.w[2]) : "v"(p[2 + kf][0]), "v"(p[2 + kf][1]));
        asm("v_cvt_pk_bf16_f32 %0, %1, %2" : "=v"(pu.w[3]) : "v"(p[2 + kf][2]), "v"(p[2 + kf][3]));
        pa[kf] = pu.v;
      }

      // ---- l += P @ ones; PV: O(16x128) += P(16x64) V(64x128) ----
      __builtin_amdgcn_s_setprio(1);
      lacc = __builtin_amdgcn_mfma_f32_16x16x32_bf16(pa[0], ones, lacc, 0, 0, 0);
      lacc = __builtin_amdgcn_mfma_f32_16x16x32_bf16(pa[1], ones, lacc, 0, 0, 0);
      #pragma unroll
      for (int jj = 0; jj < 8; ++jj)
        #pragma unroll
        for (int kf = 0; kf < 2; ++kf) {
          int rv = jj * 16 + fr;
          int off = (rv * 128 + kf * 64 + fq * 16) ^ ((rv & 7) << 4);
          bf16x8 vf = *(const bf16x8*)((const char*)Vs[cur] + off);
          ao[jj] = __builtin_amdgcn_mfma_f32_16x16x32_bf16(pa[kf], vf, ao[jj], 0, 0, 0);
        }
      __builtin_amdgcn_s_setprio(0);
    }
    asm volatile("s_barrier" ::: "memory");
    cur ^= 1;
  }

  #pragma unroll
  for (int i = 0; i < 4; ++i) {
    float inv = 1.f / lacc[i];
    int s = qw + fq * 4 + i;
    size_t base = (size_t)(b * SEQ + s) * HID + h * HD;
    #pragma unroll
    for (int jj = 0; jj < 8; ++jj)
      O[base + jj * 16 + fr] = f2bf(ao[jj][i] * inv);
  }
}

// k_out v2 (r7-proven, 43.6us): 128x128 tile, BK=128, single-buffered 64KB ->
// 2 blocks/CU (grid 512 = 2/CU; sibling hides the drain, m114), both-sides XOR swizzle.
__global__ void __launch_bounds__(256) k_out(const u16* __restrict__ at, const u16* __restrict__ woT,
    float* __restrict__ out) {
  __shared__ __align__(16) u16 As[128 * 128];   // 32KB, [row][128k], swz
  __shared__ __align__(16) u16 Bs[128 * 128];   // 32KB
  const int rb = blockIdx.x * 128, cb = blockIdx.y * 128;
  const int tid = threadIdx.x, lane = tid & 63, wave = tid >> 6;
  const int wm = wave & 1, wn = wave >> 1;
  const int fr = lane & 15, fq = lane >> 4;
  const char* Ab = (const char*)at;   // row stride 4096B
  const char* Bb = (const char*)woT;

  f32x4 acc[4][4] = {};

  for (int kt = 0; kt < HID; kt += 128) {
    __syncthreads();
    #pragma unroll
    for (int cc = 0; cc < 8; ++cc) {
      int c = wave * 8 + cc;
      int L = c * 1024 + lane * 16;
      int Ls = L ^ (((L >> 8) & 7) << 4);
      int r = Ls >> 8, colb = Ls & 255;
      load_lds16(Ab + (size_t)(rb + r) * (HID * 2) + kt * 2 + colb, (char*)As + c * 1024);
      load_lds16(Bb + (size_t)(cb + r) * (HID * 2) + kt * 2 + colb, (char*)Bs + c * 1024);
    }
    asm volatile("s_waitcnt vmcnt(0)" ::: "memory");
    __syncthreads();

    #pragma unroll
    for (int kk = 0; kk < 4; ++kk) {
      bf16x8 af[4], bfr[4];
      #pragma unroll
      for (int m = 0; m < 4; ++m) {
        int r = wm * 64 + m * 16 + fr;
        af[m] = *(const bf16x8*)((const char*)As + ((r * 256 + kk * 64 + fq * 16) ^ ((r & 7) << 4)));
      }
      #pragma unroll
      for (int n = 0; n < 4; ++n) {
        int r = wn * 64 + n * 16 + fr;
        bfr[n] = *(const bf16x8*)((const char*)Bs + ((r * 256 + kk * 64 + fq * 16) ^ ((r & 7) << 4)));
      }
      #pragma unroll
      for (int m = 0; m < 4; ++m)
        #pragma unroll
        for (int n = 0; n < 4; ++n)
          acc[m][n] = __builtin_amdgcn_mfma_f32_16x16x32_bf16(af[m], bfr[n], acc[m][n], 0, 0, 0);
    }
  }

  #pragma unroll
  for (int m = 0; m < 4; ++m)
    #pragma unroll
    for (int n = 0; n < 4; ++n)
      #pragma unroll
      for (int i = 0; i < 4; ++i)
        out[(size_t)(rb + wm * 64 + m * 16 + fq * 4 + i) * HID + cb + wn * 64 + n * 16 + fr] =
            acc[m][n][i];
}

extern "C" void kernel_launch(void* const* d_in, const int* in_sizes, int n_in,
                              void* d_out, int out_size, void* d_ws, size_t ws_size,
                              hipStream_t stream) {
  const float* x    = (const float*)d_in[0];
  const float* wqd  = (const float*)d_in[1];
  const float* wkvd = (const float*)d_in[2];
  const float* wqu  = (const float*)d_in[3];
  const float* wku  = (const float*)d_in[4];
  const float* wvu  = (const float*)d_in[5];
  const float* wo   = (const float*)d_in[6];
  float* out = (float*)d_out;

  char* p = (char*)d_ws;
  u16* xb    = (u16*)(p + 0);
  u16* at    = xb;
  u16* wqdT  = (u16*)(p + 16777216);
  u16* wkvdT = (u16*)(p + 17825792);
  u16* wquT  = (u16*)(p + 18874368);
  u16* wkuT  = (u16*)(p + 19922944);
  u16* wvuT  = (u16*)(p + 20971520);
  u16* woT   = (u16*)(p + 22020096);
  u16* ql    = (u16*)(p + 30408704);
  u16* kvl   = (u16*)(p + 32505856);
  u16* q     = (u16*)(p + 34603008);
  u16* kk    = (u16*)(p + 51380224);
  u16* vt    = (u16*)(p + 68157440);
  float* cosT = (float*)(p + 84934656);
  float* sinT = (float*)(p + 85196800);

  k_prep<<<15104, 256, 0, stream>>>(x, xb, wqd, wkvd, wqu, wku, wvu, wo,
                                    wqdT, wkvdT, wquT, wkuT, wvuT, woT, cosT, sinT);

  k_down<<<dim3(32, 4, 2), 512, 0, stream>>>(xb, wqdT, wkvdT, ql, kvl);
  k_up<<<dim3(32, 16, 3), 256, 0, stream>>>(ql, kvl, wquT, wkuT, wvuT, q, kk, vt, cosT, sinT);
  k_attn<<<256, 1024, 0, stream>>>(q, kk, vt, at);
  k_out<<<dim3(32, 16), 256, 0, stream>>>(at, woT, out);
}

// Round 20
// 138.514 us; speedup vs baseline: 1.2220x; 1.0042x over previous
//
#include <hip/hip_runtime.h>
#include <hip/hip_bf16.h>

typedef unsigned short u16;
typedef unsigned int u32;
typedef __attribute__((ext_vector_type(8))) __bf16 bf16x8;
typedef __attribute__((ext_vector_type(4))) float f32x4;

#define HID 2048
#define NH 16
#define HD 128
#define LAT 256
#define BATCH 4
#define SEQ 1024

__device__ __forceinline__ u16 f2bf(float f) {
  union { float f; u32 u; } v; v.f = f;
  u32 r = v.u + 0x7fffu + ((v.u >> 16) & 1u);
  return (u16)(r >> 16);
}

typedef const __attribute__((address_space(1))) u32 as1_u32;
typedef __attribute__((address_space(3))) u32 as3_u32;

__device__ __forceinline__ void load_lds16(const void* g, void* l) {
  __builtin_amdgcn_global_load_lds((as1_u32*)g, (as3_u32*)l, 16, 0, 0);
}

// ---------------- merged prep kernel (r16-proven) ----------------
__device__ __forceinline__ void prep_transpose(const float* __restrict__ in, u16* __restrict__ o,
                                               int R, int C, int bxi, int byi, int tid) {
  __shared__ float t[32][33];
  int bx = bxi * 32, by = byi * 32;
  int tx = tid & 31, ty = tid >> 5;
  #pragma unroll
  for (int i = ty; i < 32; i += 8) t[i][tx] = in[(size_t)(by + i) * C + bx + tx];
  __syncthreads();
  #pragma unroll
  for (int i = ty; i < 32; i += 8) o[(size_t)(bx + i) * R + by + tx] = f2bf(t[tx][i]);
}

__global__ void __launch_bounds__(256) k_prep(const float* __restrict__ x, u16* __restrict__ xb,
    const float* __restrict__ wqd, const float* __restrict__ wkvd,
    const float* __restrict__ wqu, const float* __restrict__ wku, const float* __restrict__ wvu,
    const float* __restrict__ wo,
    u16* __restrict__ wqdT, u16* __restrict__ wkvdT,
    u16* __restrict__ wquT, u16* __restrict__ wkuT, u16* __restrict__ wvuT,
    u16* __restrict__ woT, float* __restrict__ cosT, float* __restrict__ sinT) {
  const int bb = blockIdx.x, tid = threadIdx.x;
  if (bb < 8192) {
    int i = bb * 256 + tid;
    float4 v = ((const float4*)x)[i];
    union { u16 s[4]; uint2 u; } w;
    w.s[0] = f2bf(v.x); w.s[1] = f2bf(v.y); w.s[2] = f2bf(v.z); w.s[3] = f2bf(v.w);
    ((uint2*)xb)[i] = w.u;
  } else if (bb < 9216) {
    int i = bb - 8192;
    int z = i >> 9, r = i & 511;
    prep_transpose(z ? wkvd : wqd, z ? wkvdT : wqdT, 2048, 256, r & 7, r >> 3, tid);
  } else if (bb < 10752) {
    int i = bb - 9216;
    int z = i >> 9, r = i & 511;
    const float* in = (z == 0) ? wqu : (z == 1 ? wku : wvu);
    u16* o = (z == 0) ? wquT : (z == 1 ? wkuT : wvuT);
    prep_transpose(in, o, 256, 2048, r & 63, r >> 6, tid);
  } else if (bb < 14848) {
    int i = bb - 10752;
    prep_transpose(wo, woT, 2048, 2048, i & 63, i >> 6, tid);
  } else {
    int idx = (bb - 14848) * 256 + tid;
    int s = idx >> 6, d = idx & 63;
    float inv = powf(100000.0f, -(float)d / 64.0f);
    float a = (float)s * inv;
    cosT[idx] = cosf(a);
    sinT[idx] = sinf(a);
  }
}

// ---------------- stage kernels ----------------
// k_down v2 (r9-proven): 128x64 tile, BK=128, 8 waves, double-buffered counted-vmcnt.
__global__ void __launch_bounds__(512, 2) k_down(const u16* __restrict__ xb, const u16* __restrict__ wqdT,
    const u16* __restrict__ wkvdT, u16* __restrict__ ql, u16* __restrict__ kvl) {
  __shared__ __align__(16) u16 As[2][128 * 128];
  __shared__ __align__(16) u16 Bs[2][64 * 128];
  const u16* Bt = blockIdx.z ? wkvdT : wqdT;
  u16* out = blockIdx.z ? kvl : ql;
  const int rb = blockIdx.x * 128, cb = blockIdx.y * 64;
  const int tid = threadIdx.x, lane = tid & 63, wave = tid >> 6;
  const int wm = wave & 3, wn = wave >> 2;
  const int fr = lane & 15, fq = lane >> 4;
  const char* Ab = (const char*)xb;
  const char* Bb = (const char*)Bt;
  f32x4 acc[2][2] = {};

  auto stage = [&](int buf, int s) {
    #pragma unroll
    for (int cc = 0; cc < 4; ++cc) {
      int c = wave * 4 + cc;
      int L = c * 1024 + lane * 16;
      int Ls = L ^ (((L >> 8) & 7) << 4);
      int r = Ls >> 8, colb = Ls & 255;
      load_lds16(Ab + (size_t)(rb + r) * 4096 + s * 256 + colb, (char*)As[buf] + c * 1024);
    }
    #pragma unroll
    for (int cc = 0; cc < 2; ++cc) {
      int c = wave * 2 + cc;
      int L = c * 1024 + lane * 16;
      int Ls = L ^ (((L >> 8) & 7) << 4);
      int r = Ls >> 8, colb = Ls & 255;
      load_lds16(Bb + (size_t)(cb + r) * 4096 + s * 256 + colb, (char*)Bs[buf] + c * 1024);
    }
  };

  stage(0, 0);
  int buf = 0;
  for (int s = 0; s < 16; ++s) {
    if (s + 1 < 16) {
      stage(buf ^ 1, s + 1);
      asm volatile("s_waitcnt vmcnt(6)" ::: "memory");
    } else {
      asm volatile("s_waitcnt vmcnt(0)" ::: "memory");
    }
    asm volatile("s_barrier" ::: "memory");

    #pragma unroll
    for (int kk = 0; kk < 4; ++kk) {
      bf16x8 af[2], bfr[2];
      #pragma unroll
      for (int m = 0; m < 2; ++m) {
        int r = wm * 32 + m * 16 + fr;
        af[m] = *(const bf16x8*)((const char*)As[buf] + ((r * 256 + kk * 64 + fq * 16) ^ ((r & 7) << 4)));
      }
      #pragma unroll
      for (int n = 0; n < 2; ++n) {
        int r = wn * 32 + n * 16 + fr;
        bfr[n] = *(const bf16x8*)((const char*)Bs[buf] + ((r * 256 + kk * 64 + fq * 16) ^ ((r & 7) << 4)));
      }
      #pragma unroll
      for (int m = 0; m < 2; ++m)
        #pragma unroll
        for (int n = 0; n < 2; ++n)
          acc[m][n] = __builtin_amdgcn_mfma_f32_16x16x32_bf16(af[m], bfr[n], acc[m][n], 0, 0, 0);
    }

    asm volatile("s_barrier" ::: "memory");
    buf ^= 1;
  }

  #pragma unroll
  for (int m = 0; m < 2; ++m)
    #pragma unroll
    for (int n = 0; n < 2; ++n)
      #pragma unroll
      for (int i = 0; i < 4; ++i)
        out[(size_t)(rb + wm * 32 + m * 16 + fq * 4 + i) * LAT + cb + wn * 32 + n * 16 + fr] =
            f2bf(acc[m][n][i]);
}

// k_up v2 (r17-proven): 128x128 tile (one head), BK=64, dbuf counted-vmcnt(8), 4 waves.
__global__ void __launch_bounds__(256, 2) k_up(const u16* __restrict__ ql, const u16* __restrict__ kvl,
    const u16* __restrict__ wquT, const u16* __restrict__ wkuT, const u16* __restrict__ wvuT,
    u16* __restrict__ q, u16* __restrict__ k, u16* __restrict__ vt,
    const float* __restrict__ cosT, const float* __restrict__ sinT) {
  __shared__ __align__(16) u16 As[2][128 * 64];
  __shared__ __align__(16) u16 Bs[2][128 * 64];
  const int mode = blockIdx.z;
  const u16* A = (mode == 0) ? ql : kvl;
  const u16* Bt = (mode == 0) ? wquT : (mode == 1 ? wkuT : wvuT);
  const int rb = blockIdx.x * 128;
  const int h = blockIdx.y;
  const int tid = threadIdx.x, lane = tid & 63, wave = tid >> 6;
  const int fr = lane & 15, fq = lane >> 4;
  const char* Ab = (const char*)A;
  const char* Bb = (const char*)Bt;
  f32x4 acc[2][8] = {};

  auto stage = [&](int buf, int s) {
    #pragma unroll
    for (int cc = 0; cc < 4; ++cc) {
      int c = wave * 4 + cc;
      int L = c * 1024 + lane * 16;
      int Ls = L ^ (((L >> 7) & 7) << 4);
      int r = Ls >> 7, colb = Ls & 127;
      load_lds16(Ab + (size_t)(rb + r) * 512 + s * 128 + colb, (char*)As[buf] + c * 1024);
      load_lds16(Bb + (size_t)(h * HD + r) * 512 + s * 128 + colb, (char*)Bs[buf] + c * 1024);
    }
  };

  stage(0, 0);
  int buf = 0;
  for (int s = 0; s < 4; ++s) {
    if (s + 1 < 4) {
      stage(buf ^ 1, s + 1);
      asm volatile("s_waitcnt vmcnt(8)" ::: "memory");
    } else {
      asm volatile("s_waitcnt vmcnt(0)" ::: "memory");
    }
    asm volatile("s_barrier" ::: "memory");

    #pragma unroll
    for (int kk = 0; kk < 2; ++kk) {
      bf16x8 af[2], bfr[8];
      #pragma unroll
      for (int m = 0; m < 2; ++m) {
        int r = wave * 32 + m * 16 + fr;
        af[m] = *(const bf16x8*)((const char*)As[buf] + ((r * 128 + kk * 64 + fq * 16) ^ ((r & 7) << 4)));
      }
      #pragma unroll
      for (int n = 0; n < 8; ++n) {
        int r = n * 16 + fr;
        bfr[n] = *(const bf16x8*)((const char*)Bs[buf] + ((r * 128 + kk * 64 + fq * 16) ^ ((r & 7) << 4)));
      }
      #pragma unroll
      for (int m = 0; m < 2; ++m)
        #pragma unroll
        for (int n = 0; n < 8; ++n)
          acc[m][n] = __builtin_amdgcn_mfma_f32_16x16x32_bf16(af[m], bfr[n], acc[m][n], 0, 0, 0);
    }

    asm volatile("s_barrier" ::: "memory");
    buf ^= 1;
  }

  if (mode == 2) {
    #pragma unroll
    for (int m = 0; m < 2; ++m)
      #pragma unroll
      for (int n = 0; n < 8; ++n)
        #pragma unroll
        for (int i = 0; i < 4; ++i) {
          int row = rb + wave * 32 + m * 16 + fq * 4 + i;
          int b = row >> 10, s = row & 1023;
          int sp = (s & ~63) | (((s >> 4) & 1) << 5) | (((s >> 3) & 1) << 4) |
                   (((s >> 2) & 1) << 3) | (((s >> 5) & 1) << 2) | (s & 3);
          vt[(size_t)((b * NH + h) * HD + n * 16 + fr) * SEQ + sp] = f2bf(acc[m][n][i]);
        }
  } else {
    u16* dst = (mode == 0) ? q : k;
    const float scale = (mode == 0) ? 0.08838834764831845f * 1.4426950408889634f : 1.0f;
    #pragma unroll
    for (int m = 0; m < 2; ++m)
      #pragma unroll
      for (int i = 0; i < 4; ++i) {
        int row = rb + wave * 32 + m * 16 + fq * 4 + i;
        int b = row >> 10, s = row & 1023;
        size_t base = (size_t)((b * NH + h) * SEQ + s) * HD;
        #pragma unroll
        for (int j = 0; j < 4; ++j) {
          int dlo = j * 16 + fr;
          float c = cosT[s * 64 + dlo], sn = sinT[s * 64 + dlo];
          float x1 = acc[m][j][i], x2 = acc[m][j + 4][i];
          dst[base + dlo] = f2bf((x1 * c - x2 * sn) * scale);
          dst[base + dlo + 64] = f2bf((x2 * c + x1 * sn) * scale);
        }
      }
  }
}

// flash attention v11 (r13-proven, best): 256 blocks x 16 waves (1024 thr), 1 block/CU =
// 4 waves/SIMD. Waves 0-7 own q-tile jh=7-jp, waves 8-15 own jl=jp; both halves share
// staged K/V tiles. KVBLK=64 dbuf (64KB), counted vmcnt(2); in-register P (swapped
// QK^T + kappa V); XCD-local bh; shift-free exp2 softmax; ones-trick row-sum; setprio.
// NOTE: 16-wave shell caps VGPR at 128 — ONLY this exact body fits; any widening
// (32-row waves r14, KVBLK=128 r18) spills to scratch and doubles the runtime.
__global__ void __launch_bounds__(1024, 1) k_attn(const u16* __restrict__ Q, const u16* __restrict__ Kc,
    const u16* __restrict__ Vt, u16* __restrict__ O) {
  __shared__ __align__(16) u16 Ks[2][64 * 128];   // row=256B, swz bits4-6 ^ (row&7)
  __shared__ __align__(16) u16 Vs[2][128 * 64];   // [d][kappa(k)], row=128B, swz
  const int f = blockIdx.x;                       // 256 blocks
  const int bh = (f & 7) * 8 + ((f >> 3) & 7);    // 8 bh per XCD (L2 locality)
  const int jp = f >> 6;                          // 0..3
  const int jh = 7 - jp, jl = jp;
  const int h = bh & (NH - 1), b = bh >> 4;
  const int tid = threadIdx.x, lane = tid & 63, wave = tid >> 6;  // wave 0..15
  const int fr = lane & 15, fq = lane >> 4;
  const int qw = ((wave < 8) ? jh : jl) * 128 + (wave & 7) * 16;  // wave's 16 q-rows
  const size_t qkb = (size_t)bh * SEQ * HD;
  const char* Kbase = (const char*)Kc + qkb * 2;
  const char* Vbase = (const char*)Vt + (size_t)bh * HD * SEQ * 2;
  const int nkt = 2 * jh + 2;                     // heavy tile count (block-wide)

  auto stage = [&](int buf, int kt) {             // 2 loads per wave (1 K + 1 V)
    int c = wave;
    int L = c * 1024 + lane * 16;
    int Lk = L ^ (((L >> 8) & 7) << 4);
    load_lds16(Kbase + (size_t)kt * 16384 + Lk, (char*)Ks[buf] + c * 1024);
    int Lv = L ^ (((L >> 7) & 7) << 4);
    int rv = Lv >> 7, colb = Lv & 127;
    load_lds16(Vbase + (size_t)rv * (SEQ * 2) + (size_t)kt * 128 + colb, (char*)Vs[buf] + c * 1024);
  };

  bf16x8 ones;
  #pragma unroll
  for (int z = 0; z < 8; ++z) ones[z] = (__bf16)1.0f;

  bf16x8 qf[4];
  #pragma unroll
  for (int c = 0; c < 4; ++c)
    qf[c] = *(const bf16x8*)&Q[qkb + (size_t)(qw + fr) * HD + c * 32 + fq * 8];

  f32x4 ao[8] = {};
  f32x4 lacc = {};

  stage(0, 0);

  int cur = 0;
  for (int t = 0; t < nkt; ++t) {
    if (t + 1 < nkt) {
      stage(cur ^ 1, t + 1);
      asm volatile("s_waitcnt vmcnt(2)" ::: "memory");
    } else {
      asm volatile("s_waitcnt vmcnt(0)" ::: "memory");
    }
    asm volatile("s_barrier" ::: "memory");

    const int k0 = t * 64;
    if (k0 <= qw + 15) {
      // ---- QK^T (swapped): sc[n] = S^T tile; thread: k=n*16+fq*4+i, q=fr ----
      f32x4 sc[4] = {};
      __builtin_amdgcn_s_setprio(1);
      #pragma unroll
      for (int c = 0; c < 4; ++c)
        #pragma unroll
        for (int n = 0; n < 4; ++n) {
          int rr = n * 16 + fr;
          int off = (rr * 256 + c * 64 + fq * 16) ^ ((rr & 7) << 4);
          bf16x8 kf = *(const bf16x8*)((const char*)Ks[cur] + off);
          sc[n] = __builtin_amdgcn_mfma_f32_16x16x32_bf16(kf, qf[c], sc[n], 0, 0, 0);
        }
      __builtin_amdgcn_s_setprio(0);

      // ---- in-register softmax ----
      const bool needmask = (k0 + 63 > qw);
      const int qrow = qw + fr;
      float p[4][4];
      #pragma unroll
      for (int n = 0; n < 4; ++n)
        #pragma unroll
        for (int i = 0; i < 4; ++i) {
          float sv = sc[n][i];
          if (needmask) {
            int kg = k0 + n * 16 + fq * 4 + i;
            sv = (kg <= qrow) ? sv : -1e30f;
          }
          p[n][i] = exp2f(sv);
        }
      bf16x8 pa[2];
      #pragma unroll
      for (int kf = 0; kf < 2; ++kf) {
        union { bf16x8 v; u32 w[4]; } pu;
        asm("v_cvt_pk_bf16_f32 %0, %1, %2" : "=v"(pu.w[0]) : "v"(p[kf][0]), "v"(p[kf][1]));
        asm("v_cvt_pk_bf16_f32 %0, %1, %2" : "=v"(pu.w[1]) : "v"(p[kf][2]), "v"(p[kf][3]));
        asm("v_cvt_pk_bf16_f32 %0, %1, %2" : "=v"(pu.w[2]) : "v"(p[2 + kf][0]), "v"(p[2 + kf][1]));
        asm("v_cvt_pk_bf16_f32 %0, %1, %2" : "=v"(pu.w[3]) : "v"(p[2 + kf][2]), "v"(p[2 + kf][3]));
        pa[kf] = pu.v;
      }

      // ---- l += P @ ones; PV: O(16x128) += P(16x64) V(64x128) ----
      __builtin_amdgcn_s_setprio(1);
      lacc = __builtin_amdgcn_mfma_f32_16x16x32_bf16(pa[0], ones, lacc, 0, 0, 0);
      lacc = __builtin_amdgcn_mfma_f32_16x16x32_bf16(pa[1], ones, lacc, 0, 0, 0);
      #pragma unroll
      for (int jj = 0; jj < 8; ++jj)
        #pragma unroll
        for (int kf = 0; kf < 2; ++kf) {
          int rv = jj * 16 + fr;
          int off = (rv * 128 + kf * 64 + fq * 16) ^ ((rv & 7) << 4);
          bf16x8 vf = *(const bf16x8*)((const char*)Vs[cur] + off);
          ao[jj] = __builtin_amdgcn_mfma_f32_16x16x32_bf16(pa[kf], vf, ao[jj], 0, 0, 0);
        }
      __builtin_amdgcn_s_setprio(0);
    }
    asm volatile("s_barrier" ::: "memory");
    cur ^= 1;
  }

  #pragma unroll
  for (int i = 0; i < 4; ++i) {
    float inv = 1.f / lacc[i];
    int s = qw + fq * 4 + i;
    size_t base = (size_t)(b * SEQ + s) * HID + h * HD;
    #pragma unroll
    for (int jj = 0; jj < 8; ++jj)
      O[base + jj * 16 + fr] = f2bf(ao[jj][i] * inv);
  }
}

// k_out v7: r7 body + T1 XCD-region swizzle. 512 1-D blocks; region r8 = f&7 lands on
// XCD r8 (round-robin dispatch); each region = 8x8 tile cluster (1024 at-rows x 1024
// woT-rows = 4MB+4MB footprint vs whole-matrix before) -> per-XCD L2 reuse.
// Body identical to the proven 43.6us version: 128x128 tile, BK=128, single-buffered
// 64KB (2 blocks/CU; sibling hides drain, m114), both-sides XOR swizzle.
__global__ void __launch_bounds__(256) k_out(const u16* __restrict__ at, const u16* __restrict__ woT,
    float* __restrict__ out) {
  __shared__ __align__(16) u16 As[128 * 128];   // 32KB, [row][128k], swz
  __shared__ __align__(16) u16 Bs[128 * 128];   // 32KB
  const int f = blockIdx.x;                     // 512 blocks
  const int r8 = f & 7, inner = f >> 3;         // region -> XCD; inner 0..63
  const int rt = (r8 >> 1) * 8 + (inner >> 3);  // row-tile 0..31
  const int ct = (r8 & 1) * 8 + (inner & 7);    // col-tile 0..15
  const int rb = rt * 128, cb = ct * 128;
  const int tid = threadIdx.x, lane = tid & 63, wave = tid >> 6;
  const int wm = wave & 1, wn = wave >> 1;
  const int fr = lane & 15, fq = lane >> 4;
  const char* Ab = (const char*)at;   // row stride 4096B
  const char* Bb = (const char*)woT;

  f32x4 acc[4][4] = {};

  for (int kt = 0; kt < HID; kt += 128) {
    __syncthreads();
    #pragma unroll
    for (int cc = 0; cc < 8; ++cc) {
      int c = wave * 8 + cc;
      int L = c * 1024 + lane * 16;
      int Ls = L ^ (((L >> 8) & 7) << 4);
      int r = Ls >> 8, colb = Ls & 255;
      load_lds16(Ab + (size_t)(rb + r) * (HID * 2) + kt * 2 + colb, (char*)As + c * 1024);
      load_lds16(Bb + (size_t)(cb + r) * (HID * 2) + kt * 2 + colb, (char*)Bs + c * 1024);
    }
    asm volatile("s_waitcnt vmcnt(0)" ::: "memory");
    __syncthreads();

    #pragma unroll
    for (int kk = 0; kk < 4; ++kk) {
      bf16x8 af[4], bfr[4];
      #pragma unroll
      for (int m = 0; m < 4; ++m) {
        int r = wm * 64 + m * 16 + fr;
        af[m] = *(const bf16x8*)((const char*)As + ((r * 256 + kk * 64 + fq * 16) ^ ((r & 7) << 4)));
      }
      #pragma unroll
      for (int n = 0; n < 4; ++n) {
        int r = wn * 64 + n * 16 + fr;
        bfr[n] = *(const bf16x8*)((const char*)Bs + ((r * 256 + kk * 64 + fq * 16) ^ ((r & 7) << 4)));
      }
      #pragma unroll
      for (int m = 0; m < 4; ++m)
        #pragma unroll
        for (int n = 0; n < 4; ++n)
          acc[m][n] = __builtin_amdgcn_mfma_f32_16x16x32_bf16(af[m], bfr[n], acc[m][n], 0, 0, 0);
    }
  }

  #pragma unroll
  for (int m = 0; m < 4; ++m)
    #pragma unroll
    for (int n = 0; n < 4; ++n)
      #pragma unroll
      for (int i = 0; i < 4; ++i)
        out[(size_t)(rb + wm * 64 + m * 16 + fq * 4 + i) * HID + cb + wn * 64 + n * 16 + fr] =
            acc[m][n][i];
}

extern "C" void kernel_launch(void* const* d_in, const int* in_sizes, int n_in,
                              void* d_out, int out_size, void* d_ws, size_t ws_size,
                              hipStream_t stream) {
  const float* x    = (const float*)d_in[0];
  const float* wqd  = (const float*)d_in[1];
  const float* wkvd = (const float*)d_in[2];
  const float* wqu  = (const float*)d_in[3];
  const float* wku  = (const float*)d_in[4];
  const float* wvu  = (const float*)d_in[5];
  const float* wo   = (const float*)d_in[6];
  float* out = (float*)d_out;

  char* p = (char*)d_ws;
  u16* xb    = (u16*)(p + 0);
  u16* at    = xb;
  u16* wqdT  = (u16*)(p + 16777216);
  u16* wkvdT = (u16*)(p + 17825792);
  u16* wquT  = (u16*)(p + 18874368);
  u16* wkuT  = (u16*)(p + 19922944);
  u16* wvuT  = (u16*)(p + 20971520);
  u16* woT   = (u16*)(p + 22020096);
  u16* ql    = (u16*)(p + 30408704);
  u16* kvl   = (u16*)(p + 32505856);
  u16* q     = (u16*)(p + 34603008);
  u16* kk    = (u16*)(p + 51380224);
  u16* vt    = (u16*)(p + 68157440);
  float* cosT = (float*)(p + 84934656);
  float* sinT = (float*)(p + 85196800);

  k_prep<<<15104, 256, 0, stream>>>(x, xb, wqd, wkvd, wqu, wku, wvu, wo,
                                    wqdT, wkvdT, wquT, wkuT, wvuT, woT, cosT, sinT);

  k_down<<<dim3(32, 4, 2), 512, 0, stream>>>(xb, wqdT, wkvdT, ql, kvl);
  k_up<<<dim3(32, 16, 3), 256, 0, stream>>>(ql, kvl, wquT, wkuT, wvuT, q, kk, vt, cosT, sinT);
  k_attn<<<256, 1024, 0, stream>>>(q, kk, vt, at);
  k_out<<<512, 256, 0, stream>>>(at, woT, out);
}